// Round 13
// baseline (146.279 us; speedup 1.0000x reference)
//
#include <hip/hip_runtime.h>
#include <stdint.h>

#define NB 8
#define NP 196
#define NM 2048
#define NH 768
#define NT 64
#define PPAD 224          // NP padded for MFMA-K / coalesced p
#define NROWS (NB*NP)     // 1568
#define HC 16             // h-chunks in k2a
#define HCL 48            // h per chunk (16*48 = 768)

typedef __attribute__((ext_vector_type(8))) short short8;
typedef __attribute__((ext_vector_type(4))) float floatx4;
typedef __fp16 h2 __attribute__((ext_vector_type(2)));

__device__ __forceinline__ uint16_t f2b_(float f){
    union{float f; uint32_t i;} v; v.f=f; uint32_t x=v.i;
    return (uint16_t)((x + 0x7fffu + ((x>>16)&1u))>>16);
}
__device__ __forceinline__ uint16_t f2h_(float f){
    union{__fp16 h; uint16_t u;} v; v.h = (__fp16)f; return v.u;
}
__device__ __forceinline__ h2 u2h2(uint32_t u){ union{uint32_t u; h2 h;} v; v.u=u; return v.h; }
__device__ __forceinline__ short8 ldsfrag(const uint16_t* p){
    union{ uint4 u; short8 s; } v; v.u = *(const uint4*)p; return v.s;
}
// 16-B direct global->LDS (DMA, no VGPR roundtrip). LDS dest is wave-uniform
// base; HW lands lane i at base + i*16B. (CK-style addrspace casts.)
__device__ __forceinline__ void gload16(const uint16_t* g, uint16_t* l){
    __builtin_amdgcn_global_load_lds(
        reinterpret_cast<const __attribute__((address_space(1))) uint32_t*>(
            reinterpret_cast<uintptr_t>(g)),
        reinterpret_cast<__attribute__((address_space(3))) uint32_t*>(
            reinterpret_cast<uintptr_t>(l)),
        16, 0, 0);
}

// ---------- cvt3: fp32 -> bf16 for maps, W_map, W_final ----------
__global__ __launch_bounds__(256)
void cvt3(const float* __restrict__ s0, uint16_t* __restrict__ d0, int n0,
          const float* __restrict__ s1, uint16_t* __restrict__ d1, int n1,
          const float* __restrict__ s2, uint16_t* __restrict__ d2, int n2)
{
    long i = (long)(blockIdx.x*256 + threadIdx.x)*8;
    const float* s; uint16_t* d; long j;
    if (i < n0)                { s=s0; d=d0; j=i; }
    else if (i < (long)n0+n1)  { s=s1; d=d1; j=i-n0; }
    else                       { s=s2; d=d2; j=i-n0-n1; if (j>=n2) return; }
    float4 a = *(const float4*)(s+j);
    float4 b = *(const float4*)(s+j+4);
    uint4 w;
    w.x = (uint32_t)f2b_(a.x) | ((uint32_t)f2b_(a.y)<<16);
    w.y = (uint32_t)f2b_(a.z) | ((uint32_t)f2b_(a.w)<<16);
    w.z = (uint32_t)f2b_(b.x) | ((uint32_t)f2b_(b.y)<<16);
    w.w = (uint32_t)f2b_(b.z) | ((uint32_t)f2b_(b.w)<<16);
    *(uint4*)(d+j) = w;
}

// ---------- K1 (m97-style): [mloT_f16 | G_bf16] = fm · [Wmap;Wfin]^T ----------
// 128x128 block, BK=64, 4 waves (each 64x64 = 4x4 MFMA tiles). Grid (13,12).
// Staging: global_load_lds 16B, XOR swizzle folded into the GLOBAL source index
// (LDS must stay lane-contiguous for the DMA). Frag ds_read_b128 conflict-free.
__global__ __launch_bounds__(256)
void k1_m97(const uint16_t* __restrict__ A, const uint16_t* __restrict__ Bcat,
            const float* __restrict__ bmap, uint16_t* __restrict__ mloT,
            uint16_t* __restrict__ gt)
{
    __shared__ uint16_t sA[128*64];   // 16 KB
    __shared__ uint16_t sB[128*64];   // 16 KB
    const int tid = threadIdx.x;
    const int w = tid>>6, lane = tid&63;
    const int quad = lane>>4, lq = lane&15;
    const int m0 = blockIdx.x*128, n0 = blockIdx.y*128;

    // 32 chunks (A:0-15, B:16-31), chunk c = 8 rows x 64 cols (1 KB). Wave w owns 8.
    // lane i: row-in-chunk r8 = i>>3; source col-chunk qx = (i&7) ^ r8 (swizzle).
    const int r8 = lane>>3;
    const int qx = (lane&7) ^ r8;
    const uint16_t* gsrc[8];
    uint16_t* ldst[8];
    #pragma unroll
    for (int j=0;j<8;++j){
        const int c = w*8 + j;
        if (c < 16){
            gsrc[j] = A + (size_t)(m0 + c*8 + r8)*NM + qx*8;   // overread -> wcat, valid
            ldst[j] = &sA[c*512];
        } else {
            gsrc[j] = Bcat + (size_t)(n0 + (c-16)*8 + r8)*NM + qx*8;
            ldst[j] = &sB[(c-16)*512];
        }
    }

    const int msub = (w&1)*64, nsub = (w>>1)*64;
    floatx4 acc[16];
    #pragma unroll
    for (int i=0;i<16;++i) acc[i] = (floatx4){0.f,0.f,0.f,0.f};

    for (int ks=0; ks<32; ++ks){
        #pragma unroll
        for (int j=0;j<8;++j) gload16(gsrc[j] + ks*64, ldst[j]);
        __syncthreads();                       // compiler drains vmcnt before barrier
        #pragma unroll
        for (int kk=0; kk<2; ++kk){
            short8 af[4], bf[4];
            #pragma unroll
            for (int mt=0;mt<4;++mt){
                const int r = msub + mt*16 + lq;
                af[mt] = ldsfrag(&sA[r*64 + (((kk*4+quad) ^ (lq&7))*8)]);
            }
            #pragma unroll
            for (int nt=0;nt<4;++nt){
                const int r = nsub + nt*16 + lq;
                bf[nt] = ldsfrag(&sB[r*64 + (((kk*4+quad) ^ (lq&7))*8)]);
            }
            #pragma unroll
            for (int mt=0;mt<4;++mt)
                #pragma unroll
                for (int nt=0;nt<4;++nt)
                    acc[mt*4+nt] = __builtin_amdgcn_mfma_f32_16x16x32_bf16(af[mt], bf[nt], acc[mt*4+nt], 0,0,0);
        }
        __syncthreads();
    }

    // Epilogue. C/D: col = n-side + lq, row = m-side + quad*4 + r (R6-verified).
    // row0 ≡ 0 (mod 4) and 196 ≡ 0 (mod 4) => 4-row packs never straddle b.
    if (n0 < NH){
        #pragma unroll
        for (int nt=0;nt<4;++nt){
            const int col = n0 + nsub + nt*16 + lq;
            const float bv = bmap[col];
            #pragma unroll
            for (int mt=0;mt<4;++mt){
                const int row0r = m0 + msub + mt*16 + quad*4;
                if (row0r < NROWS){
                    floatx4 c = acc[mt*4+nt];
                    const int b = row0r / NP, p0 = row0r - b*NP;
                    uint2 u;
                    u.x = (uint32_t)f2h_(c[0]+bv) | ((uint32_t)f2h_(c[1]+bv)<<16);
                    u.y = (uint32_t)f2h_(c[2]+bv) | ((uint32_t)f2h_(c[3]+bv)<<16);
                    *(uint2*)&mloT[((size_t)b*NH + col)*PPAD + p0] = u;
                }
            }
        }
    } else {
        #pragma unroll
        for (int nt=0;nt<4;++nt){
            const int h = n0 - NH + nsub + nt*16 + lq;
            #pragma unroll
            for (int mt=0;mt<4;++mt){
                const int row0r = m0 + msub + mt*16 + quad*4;
                if (row0r < NROWS){
                    floatx4 c = acc[mt*4+nt];
                    const int b = row0r / NP, p0 = row0r - b*NP;
                    uint2 u;
                    u.x = (uint32_t)f2b_(c[0]) | ((uint32_t)f2b_(c[1])<<16);
                    u.y = (uint32_t)f2b_(c[2]) | ((uint32_t)f2b_(c[3])<<16);
                    *(uint2*)&gt[((size_t)b*NH + h)*PPAD + p0] = u;
                }
            }
        }
    }
}

// ---------- K2a: partial scores, no LDS (R12-proven) ----------
__global__ __launch_bounds__(256)
void k2a(const uint16_t* __restrict__ mloT, const float* __restrict__ hid,
         const float* __restrict__ Wrect, float* __restrict__ partial)
{
    const int hcv = blockIdx.x;        // 0..15
    const int tgp = blockIdx.y;        // 0..3
    const int b   = blockIdx.z;        // 0..7
    const int tid = threadIdx.x;
    const int w   = tid >> 6;
    const int L   = tid & 63;
    const int slot = w & 1;
    const int tg   = tgp*2 + (w>>1);
    const int t0   = tg*8;
    const int Lc   = (slot && L > 47) ? 47 : L;
    const int p    = slot*128 + 2*Lc;

    float acc[8][2];
    #pragma unroll
    for (int i=0;i<8;++i){ acc[i][0]=0.f; acc[i][1]=0.f; }

    const uint16_t* mp = mloT + (size_t)b*NH*PPAD + p;
    const float*    hb = hid + ((size_t)b*NT + t0)*NH;
    const int h0 = hcv*HCL;

    #pragma unroll 4
    for (int hh=0; hh<HCL; ++hh){
        const int h = h0 + hh;
        const uint32_t m = *(const uint32_t*)(mp + (size_t)h*PPAD);
        const h2 mh = u2h2(m);
        const float m0f = (float)mh.x;
        const float m1f = (float)mh.y;
        const float wvv = Wrect[h];
        #pragma unroll
        for (int ti=0; ti<8; ++ti){
            const float hv = hb[(size_t)ti*NH + h];
            acc[ti][0] = fmaf(fmaxf(m0f+hv, 0.f), wvv, acc[ti][0]);
            acc[ti][1] = fmaf(fmaxf(m1f+hv, 0.f), wvv, acc[ti][1]);
        }
    }
    #pragma unroll
    for (int ti=0; ti<8; ++ti){
        float2 v = make_float2(acc[ti][0], acc[ti][1]);
        *(float2*)&partial[(((size_t)hcv*NB + b)*NT + t0+ti)*PPAD + p] = v;
    }
}

// ---------- K2b: reduce partials + softmax per (b,t) ----------
__global__ __launch_bounds__(256)
void k2b(const float* __restrict__ partial, float* __restrict__ attn_out,
         uint16_t* __restrict__ attnb)
{
    const int bt = blockIdx.x;
    const int tid = threadIdx.x;
    const int lane = tid & 63, wv = tid >> 6;
    __shared__ float s_red[8];

    float s = 0.f;
    if (tid < PPAD){
        #pragma unroll
        for (int hcv=0; hcv<HC; ++hcv)
            s += partial[(((size_t)hcv*NB*NT) + bt)*PPAD + tid];
    }
    float v = (tid < NP) ? s : -3.0e38f;
    #pragma unroll
    for (int off=32; off>0; off>>=1) v = fmaxf(v, __shfl_xor(v, off));
    if (lane == 0) s_red[wv] = v;
    __syncthreads();
    const float mx = fmaxf(fmaxf(s_red[0], s_red[1]), fmaxf(s_red[2], s_red[3]));
    float e = (tid < NP) ? __expf(s - mx) : 0.f;
    float r = e;
    #pragma unroll
    for (int off=32; off>0; off>>=1) r += __shfl_xor(r, off);
    if (lane == 0) s_red[4 + wv] = r;
    __syncthreads();
    const float inv = 1.f / (s_red[4] + s_red[5] + s_red[6] + s_red[7]);
    const float a = e * inv;
    if (tid < NP)   attn_out[(size_t)bt*NP + tid] = a;
    if (tid < PPAD) attnb[(size_t)bt*PPAD + tid] = (tid < NP) ? f2b_(a) : (uint16_t)0;
}

// ---------- K4: out[b,t,:] = attn[b,t,:]·G[b] + bfin + hid ----------
__global__ __launch_bounds__(64)
void k4_small(const uint16_t* __restrict__ attnb, const uint16_t* __restrict__ gt,
              const float* __restrict__ bfin, const float* __restrict__ hid,
              float* __restrict__ out)
{
    const int lane = threadIdx.x;
    const int quad = lane>>4, lq = lane&15;
    const int tt = blockIdx.x;
    const int n0 = blockIdx.y*64;
    const int b  = blockIdx.z;
    const uint16_t* aprow = attnb + ((size_t)b*NT + tt*16 + lq)*PPAD + quad*8;
    const uint16_t* bp[4];
    #pragma unroll
    for (int i=0;i<4;++i) bp[i] = gt + ((size_t)b*NH + n0 + i*16 + lq)*PPAD + quad*8;

    floatx4 acc[4];
    #pragma unroll
    for (int i=0;i<4;++i) acc[i] = (floatx4){0.f,0.f,0.f,0.f};
    #pragma unroll
    for (int ks=0; ks<7; ++ks){
        short8 Af = ldsfrag(aprow + ks*32);
        #pragma unroll
        for (int i=0;i<4;++i)
            acc[i] = __builtin_amdgcn_mfma_f32_16x16x32_bf16(Af, ldsfrag(bp[i] + ks*32), acc[i], 0,0,0);
    }
    #pragma unroll
    for (int ns=0;ns<4;++ns){
        const int col = n0 + ns*16 + lq;
        const float bv = bfin[col];
        floatx4 c = acc[ns];
        #pragma unroll
        for (int r=0;r<4;++r){
            const int row = b*NT + tt*16 + quad*4 + r;
            const size_t idx = (size_t)row*NH + col;
            out[idx] = c[r] + bv + hid[idx];
        }
    }
}

// =================== fallback (R5-proven fp32 path) ===================
__global__ __launch_bounds__(256)
void k1_map(const float* __restrict__ fm, const float* __restrict__ Wmap,
            const float* __restrict__ bmap, float* __restrict__ mlo)
{
    __shared__ float s_fm[8][NM];
    const int row0 = blockIdx.x*8;
    for (int i=threadIdx.x; i<8*NM; i+=256){
        int r=i>>11, k=i&2047;
        s_fm[r][k] = fm[(size_t)(row0+r)*NM + k];
    }
    __syncthreads();
    #pragma unroll
    for (int it=0; it<3; ++it){
        int c = threadIdx.x + it*256;
        float acc[8];
        #pragma unroll
        for(int r=0;r<8;++r) acc[r]=0.f;
        const float* wr = Wmap + (size_t)c*NM;
        for (int k=0;k<NM;k+=4){
            float4 w4 = *(const float4*)(wr + k);
            #pragma unroll
            for(int r=0;r<8;++r){
                acc[r]=fmaf(w4.x,s_fm[r][k+0],acc[r]);
                acc[r]=fmaf(w4.y,s_fm[r][k+1],acc[r]);
                acc[r]=fmaf(w4.z,s_fm[r][k+2],acc[r]);
                acc[r]=fmaf(w4.w,s_fm[r][k+3],acc[r]);
            }
        }
        float bb = bmap[c];
        for(int r=0;r<8;++r) mlo[(size_t)(row0+r)*NH + c] = acc[r]+bb;
    }
}

__global__ __launch_bounds__(256)
void k2_scores_f(const float* __restrict__ mlo, const float* __restrict__ hid,
                 const float* __restrict__ Wrect, const float* __restrict__ brect,
                 float* __restrict__ attn_out)
{
    const int b    = blockIdx.x >> 4;
    const int tg   = blockIdx.x & 15;
    const int wave = threadIdx.x >> 6;
    const int lane = threadIdx.x & 63;
    const int t    = tg*4 + wave;
    float hv[12], wv[12];
    #pragma unroll
    for (int j=0;j<12;++j){
        int h = lane + 64*j;
        hv[j] = hid[(size_t)(b*NT+t)*NH + h];
        wv[j] = Wrect[h];
    }
    __shared__ float s_sc[4][NP];
    for (int p=0;p<NP;++p){
        const float* mr = mlo + ((size_t)b*NP + p)*NH;
        float acc = 0.f;
        #pragma unroll
        for (int j=0;j<12;++j){
            float v = fmaxf(mr[lane+64*j] + hv[j], 0.f);
            acc = fmaf(v,wv[j],acc);
        }
        #pragma unroll
        for (int off=32; off>0; off>>=1) acc += __shfl_down(acc,off);
        if (lane==0) s_sc[wave][p] = acc;
    }
    __syncthreads();
    float x[4]; int pidx[4];
    #pragma unroll
    for (int i=0;i<4;++i){
        int p = lane + 64*i; pidx[i]=p;
        x[i] = (p<NP) ? s_sc[wave][p] : -3.0e38f;
    }
    float mx = fmaxf(fmaxf(x[0],x[1]),fmaxf(x[2],x[3]));
    #pragma unroll
    for (int off=32; off>0; off>>=1) mx = fmaxf(mx,__shfl_xor(mx,off));
    float sum=0.f;
    #pragma unroll
    for (int i=0;i<4;++i){ x[i] = (pidx[i]<NP) ? __expf(x[i]-mx) : 0.f; sum += x[i]; }
    #pragma unroll
    for (int off=32; off>0; off>>=1) sum += __shfl_xor(sum,off);
    const float inv = 1.f/sum;
    const size_t base = (size_t)(b*NT+t)*NP;
    #pragma unroll
    for (int i=0;i<4;++i) if (pidx[i]<NP) attn_out[base+pidx[i]] = x[i]*inv;
}

__global__ __launch_bounds__(256)
void k3_ctx(const float* __restrict__ attn, const float* __restrict__ fm,
            float* __restrict__ ctx)
{
    const int b  = blockIdx.x >> 4;
    const int tg = blockIdx.x & 15;
    __shared__ float s_a[4][NP];
    for (int i=threadIdx.x; i<4*NP; i+=256){
        int tt=i/NP, p=i-tt*NP;
        s_a[tt][p] = attn[(size_t)(b*NT + tg*4+tt)*NP + p];
    }
    __syncthreads();
    const int m0 = threadIdx.x*8;
    float acc[4][8];
    #pragma unroll
    for(int tt=0;tt<4;++tt)
        #pragma unroll
        for(int i=0;i<8;++i) acc[tt][i]=0.f;
    const float* fb = fm + (size_t)b*NP*NM + m0;
    for (int p=0;p<NP;++p){
        float4 u0 = *(const float4*)(fb + (size_t)p*NM);
        float4 u1 = *(const float4*)(fb + (size_t)p*NM + 4);
        float f[8] = {u0.x,u0.y,u0.z,u0.w,u1.x,u1.y,u1.z,u1.w};
        #pragma unroll
        for(int tt=0;tt<4;++tt){
            float a = s_a[tt][p];
            #pragma unroll
            for(int i=0;i<8;++i) acc[tt][i] = fmaf(a,f[i],acc[tt][i]);
        }
    }
    #pragma unroll
    for(int tt=0;tt<4;++tt){
        float* cr = ctx + (size_t)(b*NT + tg*4+tt)*NM + m0;
        #pragma unroll
        for(int i=0;i<8;++i) cr[i]=acc[tt][i];
    }
}

__global__ __launch_bounds__(256)
void k4_final(const float* __restrict__ ctx, const float* __restrict__ Wfin,
              const float* __restrict__ bfin, const float* __restrict__ hid,
              float* __restrict__ out)
{
    __shared__ float s_c[8][NM];
    const int row0 = blockIdx.x*8;
    for (int i=threadIdx.x; i<8*NM; i+=256){
        int r=i>>11, k=i&2047;
        s_c[r][k] = ctx[(size_t)(row0+r)*NM + k];
    }
    __syncthreads();
    #pragma unroll
    for (int it=0; it<3; ++it){
        int c = threadIdx.x + it*256;
        float acc[8];
        #pragma unroll
        for(int r=0;r<8;++r) acc[r]=0.f;
        const float* wr = Wfin + (size_t)c*NM;
        for (int k=0;k<NM;k+=4){
            float4 w4 = *(const float4*)(wr + k);
            #pragma unroll
            for(int r=0;r<8;++r){
                acc[r]=fmaf(w4.x,s_c[r][k+0],acc[r]);
                acc[r]=fmaf(w4.y,s_c[r][k+1],acc[r]);
                acc[r]=fmaf(w4.z,s_c[r][k+2],acc[r]);
                acc[r]=fmaf(w4.w,s_c[r][k+3],acc[r]);
            }
        }
        float bb = bfin[c];
        for(int r=0;r<8;++r)
            out[(size_t)(row0+r)*NH + c] = acc[r] + bb + hid[(size_t)(row0+r)*NH + c];
    }
}

extern "C" void kernel_launch(void* const* d_in, const int* in_sizes, int n_in,
                              void* d_out, int out_size, void* d_ws, size_t ws_size,
                              hipStream_t stream)
{
    const float* maps  = (const float*)d_in[0];
    const float* hid   = (const float*)d_in[1];
    const float* Wmap  = (const float*)d_in[2];
    const float* bmap  = (const float*)d_in[3];
    const float* Wfin  = (const float*)d_in[4];
    const float* bfin  = (const float*)d_in[5];
    const float* Wrect = (const float*)d_in[6];
    const float* brect = (const float*)d_in[7];

    float* out_ptr  = (float*)d_out;                  // (B,T,H) fp32
    float* attn_out = out_ptr + (size_t)NB*NT*NH;     // (B,T,P) fp32

    const int    FME    = NB*NP*NM;                   // 3,211,264
    const int    WE     = NH*NM;                      // 1,572,864
    const size_t fmb_b  = (size_t)FME*2;              // 6,422,528
    const size_t w_b    = (size_t)WE*2;               // 3,145,728 each
    const size_t mloT_b = (size_t)NB*NH*PPAD*2;       // 2,752,512
    const size_t gt_b   = (size_t)NB*NH*PPAD*2;       // 2,752,512
    const size_t atb_b  = (size_t)NB*NT*PPAD*2;       //   229,376
    const size_t need   = fmb_b + 2*w_b + mloT_b + gt_b + atb_b;  // ~17.6 MiB
    // partial (HC*NB*NT*PPAD*4 = 7.34 MB) aliases fmb+wcat (12.7 MB), dead after k1.

    if (ws_size >= need) {
        uint16_t* fmb   = (uint16_t*)d_ws;
        uint16_t* wcat  = (uint16_t*)((char*)d_ws + fmb_b);          // [Wmap;Wfin] bf16
        uint16_t* wfinb = wcat + (size_t)WE;
        uint16_t* mloT  = (uint16_t*)((char*)d_ws + fmb_b + 2*w_b);  // f16 [b][h][224]
        uint16_t* gt    = mloT + (size_t)NB*NH*PPAD;                 // bf16 [b][h][224]
        uint16_t* attnb = gt   + (size_t)NB*NH*PPAD;
        float*    partial = (float*)d_ws;                            // alias (post-k1)

        const int total8 = (FME + 2*WE)/8;
        hipLaunchKernelGGL(cvt3, dim3(total8/256), dim3(256), 0, stream,
                           maps, fmb, FME, Wmap, wcat, WE, Wfin, wfinb, WE);
        hipLaunchKernelGGL(k1_m97, dim3(13,12), dim3(256), 0, stream,
                           fmb, wcat, bmap, mloT, gt);
        hipLaunchKernelGGL(k2a, dim3(HC,4,NB), dim3(256), 0, stream,
                           mloT, hid, Wrect, partial);
        hipLaunchKernelGGL(k2b, dim3(NB*NT), dim3(256), 0, stream,
                           partial, attn_out, attnb);
        hipLaunchKernelGGL(k4_small, dim3(4,12,NB), dim3(64), 0, stream,
                           attnb, gt, bfin, hid, out_ptr);
    } else {
        // R5-proven fp32 fallback
        float* mlo = (float*)d_ws;
        float* ctx = mlo + (size_t)NB*NP*NH;
        hipLaunchKernelGGL(k1_map,     dim3(NB*NP/8),   dim3(256), 0, stream, maps, Wmap, bmap, mlo);
        hipLaunchKernelGGL(k2_scores_f,dim3(NB*(NT/4)), dim3(256), 0, stream, mlo, hid, Wrect, brect, attn_out);
        hipLaunchKernelGGL(k3_ctx,     dim3(NB*(NT/4)), dim3(256), 0, stream, attn_out, maps, ctx);
        hipLaunchKernelGGL(k4_final,   dim3(NB*NT/8),   dim3(256), 0, stream, ctx, Wfin, bfin, hid, out_ptr);
    }
}

// Round 14
// 129.797 us; speedup vs baseline: 1.1270x; 1.1270x over previous
//
#include <hip/hip_runtime.h>
#include <stdint.h>

#define NB 8
#define NP 196
#define NM 2048
#define NH 768
#define NT 64
#define PPAD 224          // NP padded for MFMA-K / coalesced p
#define NROWS (NB*NP)     // 1568
#define HC 16             // h-chunks in k2a
#define HCL 48            // h per chunk (16*48 = 768)

typedef __attribute__((ext_vector_type(8))) short short8;
typedef __attribute__((ext_vector_type(4))) float floatx4;
typedef __fp16 h2 __attribute__((ext_vector_type(2)));

__device__ __forceinline__ uint16_t f2b_(float f){
    union{float f; uint32_t i;} v; v.f=f; uint32_t x=v.i;
    return (uint16_t)((x + 0x7fffu + ((x>>16)&1u))>>16);
}
__device__ __forceinline__ uint16_t f2h_(float f){
    union{__fp16 h; uint16_t u;} v; v.h = (__fp16)f; return v.u;
}
__device__ __forceinline__ h2 u2h2(uint32_t u){ union{uint32_t u; h2 h;} v; v.u=u; return v.h; }
__device__ __forceinline__ short8 ldsfrag(const uint16_t* p){
    union{ uint4 u; short8 s; } v; v.u = *(const uint4*)p; return v.s;
}
// 16-B direct global->LDS (DMA, no VGPR roundtrip). LDS dest is wave-uniform
// base; HW lands lane i at base + i*16B.
__device__ __forceinline__ void gload16(const uint16_t* g, uint16_t* l){
    __builtin_amdgcn_global_load_lds(
        reinterpret_cast<const __attribute__((address_space(1))) uint32_t*>(
            reinterpret_cast<uintptr_t>(g)),
        reinterpret_cast<__attribute__((address_space(3))) uint32_t*>(
            reinterpret_cast<uintptr_t>(l)),
        16, 0, 0);
}

// ---------- cvt3: fp32 -> bf16 for maps, W_map, W_final ----------
__global__ __launch_bounds__(256)
void cvt3(const float* __restrict__ s0, uint16_t* __restrict__ d0, int n0,
          const float* __restrict__ s1, uint16_t* __restrict__ d1, int n1,
          const float* __restrict__ s2, uint16_t* __restrict__ d2, int n2)
{
    long i = (long)(blockIdx.x*256 + threadIdx.x)*8;
    const float* s; uint16_t* d; long j;
    if (i < n0)                { s=s0; d=d0; j=i; }
    else if (i < (long)n0+n1)  { s=s1; d=d1; j=i-n0; }
    else                       { s=s2; d=d2; j=i-n0-n1; if (j>=n2) return; }
    float4 a = *(const float4*)(s+j);
    float4 b = *(const float4*)(s+j+4);
    uint4 w;
    w.x = (uint32_t)f2b_(a.x) | ((uint32_t)f2b_(a.y)<<16);
    w.y = (uint32_t)f2b_(a.z) | ((uint32_t)f2b_(a.w)<<16);
    w.z = (uint32_t)f2b_(b.x) | ((uint32_t)f2b_(b.y)<<16);
    w.w = (uint32_t)f2b_(b.z) | ((uint32_t)f2b_(b.w)<<16);
    *(uint4*)(d+j) = w;
}

// ---------- K1 (DMA + 64x64): [mloT_f16 | G_bf16] = fm · [Wmap;Wfin]^T ----------
// 64x64 block, BK=64, 4 waves (each 32x32 = 2x2 MFMA tiles). Grid (25, 24) = 600 blocks.
// Staging: global_load_lds 16B, XOR swizzle folded into the GLOBAL source index
// (R13-verified scheme). Frag ds_read_b128 conflict-free (2-way alias only).
__global__ __launch_bounds__(256)
void k1_dma64(const uint16_t* __restrict__ A, const uint16_t* __restrict__ Bcat,
              const float* __restrict__ bmap, uint16_t* __restrict__ mloT,
              uint16_t* __restrict__ gt)
{
    __shared__ uint16_t sA[64*64];    // 8 KB
    __shared__ uint16_t sB[64*64];    // 8 KB
    const int tid = threadIdx.x;
    const int w = tid>>6, lane = tid&63;
    const int quad = lane>>4, lq = lane&15;
    const int m0 = blockIdx.x*64, n0 = blockIdx.y*64;

    // 16 chunks (A:0-7, B:8-15), chunk c = 8 rows x 64 cols (1 KB). Wave w owns 4.
    // lane i: row-in-chunk r8 = i>>3; source col-chunk qx = (i&7) ^ r8 (swizzle).
    const int r8 = lane>>3;
    const int qx = (lane&7) ^ r8;
    const uint16_t* gsrc[4];
    uint16_t* ldst[4];
    #pragma unroll
    for (int j=0;j<4;++j){
        const int c = w*4 + j;
        if (c < 8){
            // A rows may overread past NROWS into wcat (valid memory; stores masked)
            gsrc[j] = A + (size_t)(m0 + c*8 + r8)*NM + qx*8;
            ldst[j] = &sA[c*512];
        } else {
            gsrc[j] = Bcat + (size_t)(n0 + (c-8)*8 + r8)*NM + qx*8;
            ldst[j] = &sB[(c-8)*512];
        }
    }

    const int msub = (w&1)*32, nsub = (w>>1)*32;
    floatx4 acc[2][2];
    #pragma unroll
    for (int i=0;i<2;++i)
        #pragma unroll
        for (int j=0;j<2;++j) acc[i][j] = (floatx4){0.f,0.f,0.f,0.f};

    for (int ks=0; ks<32; ++ks){
        #pragma unroll
        for (int j=0;j<4;++j) gload16(gsrc[j] + ks*64, ldst[j]);
        __syncthreads();                       // compiler drains vmcnt before barrier
        #pragma unroll
        for (int kk=0; kk<2; ++kk){
            short8 af[2], bf[2];
            #pragma unroll
            for (int mt=0;mt<2;++mt){
                const int r = msub + mt*16 + lq;
                af[mt] = ldsfrag(&sA[r*64 + (((kk*4+quad) ^ (lq&7))*8)]);
            }
            #pragma unroll
            for (int nt=0;nt<2;++nt){
                const int r = nsub + nt*16 + lq;
                bf[nt] = ldsfrag(&sB[r*64 + (((kk*4+quad) ^ (lq&7))*8)]);
            }
            #pragma unroll
            for (int mt=0;mt<2;++mt)
                #pragma unroll
                for (int nt=0;nt<2;++nt)
                    acc[mt][nt] = __builtin_amdgcn_mfma_f32_16x16x32_bf16(af[mt], bf[nt], acc[mt][nt], 0,0,0);
        }
        __syncthreads();
    }

    // Epilogue. C/D: col = n-side + lq, row = m-side + quad*4 + r (R6-verified).
    // 4-row packs never straddle b (all offsets ≡ 0 mod 4).
    if (n0 < NH){
        #pragma unroll
        for (int nt=0;nt<2;++nt){
            const int col = n0 + nsub + nt*16 + lq;
            const float bv = bmap[col];
            #pragma unroll
            for (int mt=0;mt<2;++mt){
                const int row0r = m0 + msub + mt*16 + quad*4;
                if (row0r < NROWS){
                    floatx4 c = acc[mt][nt];
                    const int b = row0r / NP, p0 = row0r - b*NP;
                    uint2 u;
                    u.x = (uint32_t)f2h_(c[0]+bv) | ((uint32_t)f2h_(c[1]+bv)<<16);
                    u.y = (uint32_t)f2h_(c[2]+bv) | ((uint32_t)f2h_(c[3]+bv)<<16);
                    *(uint2*)&mloT[((size_t)b*NH + col)*PPAD + p0] = u;
                }
            }
        }
    } else {
        #pragma unroll
        for (int nt=0;nt<2;++nt){
            const int h = n0 - NH + nsub + nt*16 + lq;
            #pragma unroll
            for (int mt=0;mt<2;++mt){
                const int row0r = m0 + msub + mt*16 + quad*4;
                if (row0r < NROWS){
                    floatx4 c = acc[mt][nt];
                    const int b = row0r / NP, p0 = row0r - b*NP;
                    uint2 u;
                    u.x = (uint32_t)f2b_(c[0]) | ((uint32_t)f2b_(c[1])<<16);
                    u.y = (uint32_t)f2b_(c[2]) | ((uint32_t)f2b_(c[3])<<16);
                    *(uint2*)&gt[((size_t)b*NH + h)*PPAD + p0] = u;
                }
            }
        }
    }
}

// ---------- K2a: partial scores, no LDS (R12-proven) ----------
__global__ __launch_bounds__(256)
void k2a(const uint16_t* __restrict__ mloT, const float* __restrict__ hid,
         const float* __restrict__ Wrect, float* __restrict__ partial)
{
    const int hcv = blockIdx.x;        // 0..15
    const int tgp = blockIdx.y;        // 0..3
    const int b   = blockIdx.z;        // 0..7
    const int tid = threadIdx.x;
    const int w   = tid >> 6;
    const int L   = tid & 63;
    const int slot = w & 1;
    const int tg   = tgp*2 + (w>>1);
    const int t0   = tg*8;
    const int Lc   = (slot && L > 47) ? 47 : L;
    const int p    = slot*128 + 2*Lc;

    float acc[8][2];
    #pragma unroll
    for (int i=0;i<8;++i){ acc[i][0]=0.f; acc[i][1]=0.f; }

    const uint16_t* mp = mloT + (size_t)b*NH*PPAD + p;
    const float*    hb = hid + ((size_t)b*NT + t0)*NH;
    const int h0 = hcv*HCL;

    #pragma unroll 4
    for (int hh=0; hh<HCL; ++hh){
        const int h = h0 + hh;
        const uint32_t m = *(const uint32_t*)(mp + (size_t)h*PPAD);
        const h2 mh = u2h2(m);
        const float m0f = (float)mh.x;
        const float m1f = (float)mh.y;
        const float wvv = Wrect[h];
        #pragma unroll
        for (int ti=0; ti<8; ++ti){
            const float hv = hb[(size_t)ti*NH + h];
            acc[ti][0] = fmaf(fmaxf(m0f+hv, 0.f), wvv, acc[ti][0]);
            acc[ti][1] = fmaf(fmaxf(m1f+hv, 0.f), wvv, acc[ti][1]);
        }
    }
    #pragma unroll
    for (int ti=0; ti<8; ++ti){
        float2 v = make_float2(acc[ti][0], acc[ti][1]);
        *(float2*)&partial[(((size_t)hcv*NB + b)*NT + t0+ti)*PPAD + p] = v;
    }
}

// ---------- K2b: reduce partials + softmax per (b,t) ----------
__global__ __launch_bounds__(256)
void k2b(const float* __restrict__ partial, float* __restrict__ attn_out,
         uint16_t* __restrict__ attnb)
{
    const int bt = blockIdx.x;
    const int tid = threadIdx.x;
    const int lane = tid & 63, wv = tid >> 6;
    __shared__ float s_red[8];

    float s = 0.f;
    if (tid < PPAD){
        #pragma unroll
        for (int hcv=0; hcv<HC; ++hcv)
            s += partial[(((size_t)hcv*NB*NT) + bt)*PPAD + tid];
    }
    float v = (tid < NP) ? s : -3.0e38f;
    #pragma unroll
    for (int off=32; off>0; off>>=1) v = fmaxf(v, __shfl_xor(v, off));
    if (lane == 0) s_red[wv] = v;
    __syncthreads();
    const float mx = fmaxf(fmaxf(s_red[0], s_red[1]), fmaxf(s_red[2], s_red[3]));
    float e = (tid < NP) ? __expf(s - mx) : 0.f;
    float r = e;
    #pragma unroll
    for (int off=32; off>0; off>>=1) r += __shfl_xor(r, off);
    if (lane == 0) s_red[4 + wv] = r;
    __syncthreads();
    const float inv = 1.f / (s_red[4] + s_red[5] + s_red[6] + s_red[7]);
    const float a = e * inv;
    if (tid < NP)   attn_out[(size_t)bt*NP + tid] = a;
    if (tid < PPAD) attnb[(size_t)bt*PPAD + tid] = (tid < NP) ? f2b_(a) : (uint16_t)0;
}

// ---------- K4: out[b,t,:] = attn[b,t,:]·G[b] + bfin + hid ----------
__global__ __launch_bounds__(64)
void k4_small(const uint16_t* __restrict__ attnb, const uint16_t* __restrict__ gt,
              const float* __restrict__ bfin, const float* __restrict__ hid,
              float* __restrict__ out)
{
    const int lane = threadIdx.x;
    const int quad = lane>>4, lq = lane&15;
    const int tt = blockIdx.x;
    const int n0 = blockIdx.y*64;
    const int b  = blockIdx.z;
    const uint16_t* aprow = attnb + ((size_t)b*NT + tt*16 + lq)*PPAD + quad*8;
    const uint16_t* bp[4];
    #pragma unroll
    for (int i=0;i<4;++i) bp[i] = gt + ((size_t)b*NH + n0 + i*16 + lq)*PPAD + quad*8;

    floatx4 acc[4];
    #pragma unroll
    for (int i=0;i<4;++i) acc[i] = (floatx4){0.f,0.f,0.f,0.f};
    #pragma unroll
    for (int ks=0; ks<7; ++ks){
        short8 Af = ldsfrag(aprow + ks*32);
        #pragma unroll
        for (int i=0;i<4;++i)
            acc[i] = __builtin_amdgcn_mfma_f32_16x16x32_bf16(Af, ldsfrag(bp[i] + ks*32), acc[i], 0,0,0);
    }
    #pragma unroll
    for (int ns=0;ns<4;++ns){
        const int col = n0 + ns*16 + lq;
        const float bv = bfin[col];
        floatx4 c = acc[ns];
        #pragma unroll
        for (int r=0;r<4;++r){
            const int row = b*NT + tt*16 + quad*4 + r;
            const size_t idx = (size_t)row*NH + col;
            out[idx] = c[r] + bv + hid[idx];
        }
    }
}

// =================== fallback (R5-proven fp32 path) ===================
__global__ __launch_bounds__(256)
void k1_map(const float* __restrict__ fm, const float* __restrict__ Wmap,
            const float* __restrict__ bmap, float* __restrict__ mlo)
{
    __shared__ float s_fm[8][NM];
    const int row0 = blockIdx.x*8;
    for (int i=threadIdx.x; i<8*NM; i+=256){
        int r=i>>11, k=i&2047;
        s_fm[r][k] = fm[(size_t)(row0+r)*NM + k];
    }
    __syncthreads();
    #pragma unroll
    for (int it=0; it<3; ++it){
        int c = threadIdx.x + it*256;
        float acc[8];
        #pragma unroll
        for(int r=0;r<8;++r) acc[r]=0.f;
        const float* wr = Wmap + (size_t)c*NM;
        for (int k=0;k<NM;k+=4){
            float4 w4 = *(const float4*)(wr + k);
            #pragma unroll
            for(int r=0;r<8;++r){
                acc[r]=fmaf(w4.x,s_fm[r][k+0],acc[r]);
                acc[r]=fmaf(w4.y,s_fm[r][k+1],acc[r]);
                acc[r]=fmaf(w4.z,s_fm[r][k+2],acc[r]);
                acc[r]=fmaf(w4.w,s_fm[r][k+3],acc[r]);
            }
        }
        float bb = bmap[c];
        for(int r=0;r<8;++r) mlo[(size_t)(row0+r)*NH + c] = acc[r]+bb;
    }
}

__global__ __launch_bounds__(256)
void k2_scores_f(const float* __restrict__ mlo, const float* __restrict__ hid,
                 const float* __restrict__ Wrect, const float* __restrict__ brect,
                 float* __restrict__ attn_out)
{
    const int b    = blockIdx.x >> 4;
    const int tg   = blockIdx.x & 15;
    const int wave = threadIdx.x >> 6;
    const int lane = threadIdx.x & 63;
    const int t    = tg*4 + wave;
    float hv[12], wv[12];
    #pragma unroll
    for (int j=0;j<12;++j){
        int h = lane + 64*j;
        hv[j] = hid[(size_t)(b*NT+t)*NH + h];
        wv[j] = Wrect[h];
    }
    __shared__ float s_sc[4][NP];
    for (int p=0;p<NP;++p){
        const float* mr = mlo + ((size_t)b*NP + p)*NH;
        float acc = 0.f;
        #pragma unroll
        for (int j=0;j<12;++j){
            float v = fmaxf(mr[lane+64*j] + hv[j], 0.f);
            acc = fmaf(v,wv[j],acc);
        }
        #pragma unroll
        for (int off=32; off>0; off>>=1) acc += __shfl_down(acc,off);
        if (lane==0) s_sc[wave][p] = acc;
    }
    __syncthreads();
    float x[4]; int pidx[4];
    #pragma unroll
    for (int i=0;i<4;++i){
        int p = lane + 64*i; pidx[i]=p;
        x[i] = (p<NP) ? s_sc[wave][p] : -3.0e38f;
    }
    float mx = fmaxf(fmaxf(x[0],x[1]),fmaxf(x[2],x[3]));
    #pragma unroll
    for (int off=32; off>0; off>>=1) mx = fmaxf(mx,__shfl_xor(mx,off));
    float sum=0.f;
    #pragma unroll
    for (int i=0;i<4;++i){ x[i] = (pidx[i]<NP) ? __expf(x[i]-mx) : 0.f; sum += x[i]; }
    #pragma unroll
    for (int off=32; off>0; off>>=1) sum += __shfl_xor(sum,off);
    const float inv = 1.f/sum;
    const size_t base = (size_t)(b*NT+t)*NP;
    #pragma unroll
    for (int i=0;i<4;++i) if (pidx[i]<NP) attn_out[base+pidx[i]] = x[i]*inv;
}

__global__ __launch_bounds__(256)
void k3_ctx(const float* __restrict__ attn, const float* __restrict__ fm,
            float* __restrict__ ctx)
{
    const int b  = blockIdx.x >> 4;
    const int tg = blockIdx.x & 15;
    __shared__ float s_a[4][NP];
    for (int i=threadIdx.x; i<4*NP; i+=256){
        int tt=i/NP, p=i-tt*NP;
        s_a[tt][p] = attn[(size_t)(b*NT + tg*4+tt)*NP + p];
    }
    __syncthreads();
    const int m0 = threadIdx.x*8;
    float acc[4][8];
    #pragma unroll
    for(int tt=0;tt<4;++tt)
        #pragma unroll
        for(int i=0;i<8;++i) acc[tt][i]=0.f;
    const float* fb = fm + (size_t)b*NP*NM + m0;
    for (int p=0;p<NP;++p){
        float4 u0 = *(const float4*)(fb + (size_t)p*NM);
        float4 u1 = *(const float4*)(fb + (size_t)p*NM + 4);
        float f[8] = {u0.x,u0.y,u0.z,u0.w,u1.x,u1.y,u1.z,u1.w};
        #pragma unroll
        for(int tt=0;tt<4;++tt){
            float a = s_a[tt][p];
            #pragma unroll
            for(int i=0;i<8;++i) acc[tt][i] = fmaf(a,f[i],acc[tt][i]);
        }
    }
    #pragma unroll
    for(int tt=0;tt<4;++tt){
        float* cr = ctx + (size_t)(b*NT + tg*4+tt)*NM + m0;
        #pragma unroll
        for(int i=0;i<8;++i) cr[i]=acc[tt][i];
    }
}

__global__ __launch_bounds__(256)
void k4_final(const float* __restrict__ ctx, const float* __restrict__ Wfin,
              const float* __restrict__ bfin, const float* __restrict__ hid,
              float* __restrict__ out)
{
    __shared__ float s_c[8][NM];
    const int row0 = blockIdx.x*8;
    for (int i=threadIdx.x; i<8*NM; i+=256){
        int r=i>>11, k=i&2047;
        s_c[r][k] = ctx[(size_t)(row0+r)*NM + k];
    }
    __syncthreads();
    #pragma unroll
    for (int it=0; it<3; ++it){
        int c = threadIdx.x + it*256;
        float acc[8];
        #pragma unroll
        for(int r=0;r<8;++r) acc[r]=0.f;
        const float* wr = Wfin + (size_t)c*NM;
        for (int k=0;k<NM;k+=4){
            float4 w4 = *(const float4*)(wr + k);
            #pragma unroll
            for(int r=0;r<8;++r){
                acc[r]=fmaf(w4.x,s_c[r][k+0],acc[r]);
                acc[r]=fmaf(w4.y,s_c[r][k+1],acc[r]);
                acc[r]=fmaf(w4.z,s_c[r][k+2],acc[r]);
                acc[r]=fmaf(w4.w,s_c[r][k+3],acc[r]);
            }
        }
        float bb = bfin[c];
        for(int r=0;r<8;++r)
            out[(size_t)(row0+r)*NH + c] = acc[r] + bb + hid[(size_t)(row0+r)*NH + c];
    }
}

extern "C" void kernel_launch(void* const* d_in, const int* in_sizes, int n_in,
                              void* d_out, int out_size, void* d_ws, size_t ws_size,
                              hipStream_t stream)
{
    const float* maps  = (const float*)d_in[0];
    const float* hid   = (const float*)d_in[1];
    const float* Wmap  = (const float*)d_in[2];
    const float* bmap  = (const float*)d_in[3];
    const float* Wfin  = (const float*)d_in[4];
    const float* bfin  = (const float*)d_in[5];
    const float* Wrect = (const float*)d_in[6];
    const float* brect = (const float*)d_in[7];

    float* out_ptr  = (float*)d_out;                  // (B,T,H) fp32
    float* attn_out = out_ptr + (size_t)NB*NT*NH;     // (B,T,P) fp32

    const int    FME    = NB*NP*NM;                   // 3,211,264
    const int    WE     = NH*NM;                      // 1,572,864
    const size_t fmb_b  = (size_t)FME*2;              // 6,422,528
    const size_t w_b    = (size_t)WE*2;               // 3,145,728 each
    const size_t mloT_b = (size_t)NB*NH*PPAD*2;       // 2,752,512
    const size_t gt_b   = (size_t)NB*NH*PPAD*2;       // 2,752,512
    const size_t atb_b  = (size_t)NB*NT*PPAD*2;       //   229,376
    const size_t need   = fmb_b + 2*w_b + mloT_b + gt_b + atb_b;  // ~17.6 MiB
    // partial (HC*NB*NT*PPAD*4 = 7.34 MB) aliases fmb+wcat (12.7 MB), dead after k1.

    if (ws_size >= need) {
        uint16_t* fmb   = (uint16_t*)d_ws;
        uint16_t* wcat  = (uint16_t*)((char*)d_ws + fmb_b);          // [Wmap;Wfin] bf16
        uint16_t* wfinb = wcat + (size_t)WE;
        uint16_t* mloT  = (uint16_t*)((char*)d_ws + fmb_b + 2*w_b);  // f16 [b][h][224]
        uint16_t* gt    = mloT + (size_t)NB*NH*PPAD;                 // bf16 [b][h][224]
        uint16_t* attnb = gt   + (size_t)NB*NH*PPAD;
        float*    partial = (float*)d_ws;                            // alias (post-k1)

        const int total8 = (FME + 2*WE)/8;
        hipLaunchKernelGGL(cvt3, dim3(total8/256), dim3(256), 0, stream,
                           maps, fmb, FME, Wmap, wcat, WE, Wfin, wfinb, WE);
        hipLaunchKernelGGL(k1_dma64, dim3(25,24), dim3(256), 0, stream,
                           fmb, wcat, bmap, mloT, gt);
        hipLaunchKernelGGL(k2a, dim3(HC,4,NB), dim3(256), 0, stream,
                           mloT, hid, Wrect, partial);
        hipLaunchKernelGGL(k2b, dim3(NB*NT), dim3(256), 0, stream,
                           partial, attn_out, attnb);
        hipLaunchKernelGGL(k4_small, dim3(4,12,NB), dim3(64), 0, stream,
                           attnb, gt, bfin, hid, out_ptr);
    } else {
        // R5-proven fp32 fallback
        float* mlo = (float*)d_ws;
        float* ctx = mlo + (size_t)NB*NP*NH;
        hipLaunchKernelGGL(k1_map,     dim3(NB*NP/8),   dim3(256), 0, stream, maps, Wmap, bmap, mlo);
        hipLaunchKernelGGL(k2_scores_f,dim3(NB*(NT/4)), dim3(256), 0, stream, mlo, hid, Wrect, brect, attn_out);
        hipLaunchKernelGGL(k3_ctx,     dim3(NB*(NT/4)), dim3(256), 0, stream, attn_out, maps, ctx);
        hipLaunchKernelGGL(k4_final,   dim3(NB*NT/8),   dim3(256), 0, stream, ctx, Wfin, bfin, hid, out_ptr);
    }
}